// Round 6
// baseline (565.077 us; speedup 1.0000x reference)
//
#include <hip/hip_runtime.h>
#include <math.h>

// LCGLoss: B=256, L=512, D=512.
// S[(b,l),k] = (text @ C^T)[(b,l),k],  Cb[k][d] = bf16( (ip @ W_ML)[k][d] / tau )
// loss = mean over valid (i,l) of 0.5*(denom_log + logaddexp(s_iji, cross_log[i])) - s_iji

#define B_ 256
#define L_ 512
#define D_ 512
#define ROWS (B_ * L_)      // 131072
#define NT2 (ROWS / 128)    // 1024 row-tiles (M=128)
#define NEG_INF (-INFINITY)

typedef __attribute__((ext_vector_type(8))) short s8_t;     // 8 bf16 in 4 VGPRs
typedef __attribute__((ext_vector_type(4))) float f4_t;
typedef __attribute__((ext_vector_type(2))) float f2_t;
typedef __attribute__((ext_vector_type(4))) unsigned short us4_t;

__device__ inline unsigned short f2bf(float x) {
    unsigned int u = __float_as_uint(x);
    u += 0x7FFFu + ((u >> 16) & 1u);          // round-to-nearest-even
    return (unsigned short)(u >> 16);
}

// ---------------- K0: ip[k][e] = sum_d img[k][d]*Wmv[e][d]; 32k x 64e tiles, 64 blocks ----
__global__ __launch_bounds__(256) void ip_kernel(const float* __restrict__ img,
                                                 const float* __restrict__ Wmv,
                                                 float* __restrict__ ip) {
    int kt = blockIdx.x >> 3, et = blockIdx.x & 7;
    __shared__ float Ast[32][36];   // [d][krow]  (transposed)
    __shared__ float Bst[32][72];   // [d][ecol]  (transposed)
    int tid = threadIdx.x;
    int ty = tid >> 4;
    int tx = tid & 15;
    float acc[2][4] = {};
    int sr = tid >> 3, sc = (tid & 7) * 4;
    for (int d0 = 0; d0 < D_; d0 += 32) {
        f4_t a = *(const f4_t*)(img + (size_t)(kt * 32 + sr) * D_ + d0 + sc);
        f4_t b0 = *(const f4_t*)(Wmv + (size_t)(et * 64 + sr) * D_ + d0 + sc);
        f4_t b1 = *(const f4_t*)(Wmv + (size_t)(et * 64 + sr + 32) * D_ + d0 + sc);
        __syncthreads();
#pragma unroll
        for (int m = 0; m < 4; m++) {
            Ast[sc + m][sr] = a[m];
            Bst[sc + m][sr] = b0[m];
            Bst[sc + m][sr + 32] = b1[m];
        }
        __syncthreads();
#pragma unroll 4
        for (int d = 0; d < 32; d++) {
            f2_t a2 = *(const f2_t*)&Ast[d][ty * 2];
            f4_t b4 = *(const f4_t*)&Bst[d][tx * 4];
#pragma unroll
            for (int i = 0; i < 2; i++)
#pragma unroll
                for (int j = 0; j < 4; j++) acc[i][j] = fmaf(a2[i], b4[j], acc[i][j]);
        }
    }
#pragma unroll
    for (int i = 0; i < 2; i++) {
        f4_t o; o[0] = acc[i][0]; o[1] = acc[i][1]; o[2] = acc[i][2]; o[3] = acc[i][3];
        *(f4_t*)(ip + (size_t)(kt * 32 + ty * 2 + i) * D_ + et * 64 + tx * 4) = o;
    }
}

// ---------------- K1: Cb[k][d] = bf16( sum_e ip[k][e]*Wml[e][d] / tau ); 64 blocks -------
__global__ __launch_bounds__(256) void c_kernel(const float* __restrict__ ip,
                                                const float* __restrict__ Wml,
                                                const float* __restrict__ tau,
                                                unsigned short* __restrict__ Cb) {
    int kt = blockIdx.x >> 3, dt = blockIdx.x & 7;
    __shared__ float Ast[32][36];
    __shared__ float Bst[32][72];
    int tid = threadIdx.x;
    int ty = tid >> 4;
    int tx = tid & 15;
    float acc[2][4] = {};
    int sr = tid >> 3, sc = (tid & 7) * 4;
    int br = tid >> 4, bc = (tid & 15) * 4;
    for (int e0 = 0; e0 < D_; e0 += 32) {
        f4_t a = *(const f4_t*)(ip + (size_t)(kt * 32 + sr) * D_ + e0 + sc);
        f4_t b0 = *(const f4_t*)(Wml + (size_t)(e0 + br) * D_ + dt * 64 + bc);
        f4_t b1 = *(const f4_t*)(Wml + (size_t)(e0 + br + 16) * D_ + dt * 64 + bc);
        __syncthreads();
#pragma unroll
        for (int m = 0; m < 4; m++) Ast[sc + m][sr] = a[m];
        *(f4_t*)&Bst[br][bc] = b0;
        *(f4_t*)&Bst[br + 16][bc] = b1;
        __syncthreads();
#pragma unroll 4
        for (int e = 0; e < 32; e++) {
            f2_t a2 = *(const f2_t*)&Ast[e][ty * 2];
            f4_t b4 = *(const f4_t*)&Bst[e][tx * 4];
#pragma unroll
            for (int i = 0; i < 2; i++)
#pragma unroll
                for (int j = 0; j < 4; j++) acc[i][j] = fmaf(a2[i], b4[j], acc[i][j]);
        }
    }
    float it = 1.0f / fmaxf(tau[0], 0.001f);
#pragma unroll
    for (int i = 0; i < 2; i++) {
        us4_t o;
#pragma unroll
        for (int j = 0; j < 4; j++) o[j] = f2bf(acc[i][j] * it);
        *(us4_t*)(Cb + (size_t)(kt * 32 + ty * 2 + i) * D_ + dt * 64 + tx * 4) = o;
    }
}

// ---------------- Kmask: mbits[l*4+w] bit j = valid[w*64+j, l] ----------------
__global__ __launch_bounds__(256) void mask_kernel(const int* __restrict__ pad,
                                                   unsigned long long* __restrict__ mbits) {
    int l = blockIdx.x;
    int w = threadIdx.x >> 6;
    int j = threadIdx.x & 63;
    unsigned long long bal = __ballot(pad[(w * 64 + j) * L_ + l] == 0);
    if (j == 0) mbits[l * 4 + w] = bal;
}

// ---------------- K2: MFMA GEMM, M=128 x N=256 per block ----------------
// A (f32 text) -> bf16 via LDS (reg-prefetch dbuf, ONE barrier per 32-k step).
// B (bf16 Cb, 256 KB, L2-resident) -> direct per-lane global fragment loads.
__global__ __launch_bounds__(256) void gemm_mfma_kernel(
    const float* __restrict__ text, const unsigned short* __restrict__ Cb,
    const unsigned long long* __restrict__ mbits,
    float* __restrict__ denom, float* __restrict__ siji,
    float* __restrict__ crossM, float* __restrict__ crossS) {
    // staging: 2 x (A 128x40 bf16 = 10240 B) = 5120 floats; epilogue overlay 8512 floats
    __shared__ __align__(16) float lds[8512];
    unsigned short* A0 = (unsigned short*)lds;
    unsigned short* A1 = A0 + 5120;
    float* Sh  = lds;
    float* pm  = lds + 8224;
    float* ps  = lds + 8352;
    float* rvadj = lds + 8480;

    const int tile = blockIdx.x;
    const int row0 = tile * 128;
    const int bIdx = row0 >> 9;       // batch index (128 | 512)
    const int l0 = row0 & 511;
    const int tid = threadIdx.x;
    const int wave = tid >> 6;
    const int lane = tid & 63;
    const int qd = lane >> 4;
    const int mm = lane & 15;

    f4_t acc[8][4];
#pragma unroll
    for (int mt = 0; mt < 8; mt++)
#pragma unroll
        for (int nt = 0; nt < 4; nt++)
#pragma unroll
            for (int r = 0; r < 4; r++) acc[mt][nt][r] = 0.f;

    // A staging: thread t covers row t>>1, k-halves (t&1)*16 .. +16 of the 32-k step
    const int arow = tid >> 1, akh = (tid & 1) * 16;
    const float* aptr = text + (size_t)(row0 + arow) * D_ + akh;
    // B fragment pointers: col = wave*64 + nt*16 + mm, k-offset qd*8
    const unsigned short* bptr = Cb + (size_t)(wave * 64 + mm) * D_ + qd * 8;

    f4_t ar0, ar1, ar2, ar3;
    ar0 = *(const f4_t*)(aptr);  ar1 = *(const f4_t*)(aptr + 4);
    ar2 = *(const f4_t*)(aptr + 8); ar3 = *(const f4_t*)(aptr + 12);
    {   // store k=0 into A0
        s8_t h0, h1;
        h0[0]=(short)f2bf(ar0[0]); h0[1]=(short)f2bf(ar0[1]); h0[2]=(short)f2bf(ar0[2]); h0[3]=(short)f2bf(ar0[3]);
        h0[4]=(short)f2bf(ar1[0]); h0[5]=(short)f2bf(ar1[1]); h0[6]=(short)f2bf(ar1[2]); h0[7]=(short)f2bf(ar1[3]);
        h1[0]=(short)f2bf(ar2[0]); h1[1]=(short)f2bf(ar2[1]); h1[2]=(short)f2bf(ar2[2]); h1[3]=(short)f2bf(ar2[3]);
        h1[4]=(short)f2bf(ar3[0]); h1[5]=(short)f2bf(ar3[1]); h1[6]=(short)f2bf(ar3[2]); h1[7]=(short)f2bf(ar3[3]);
        *(s8_t*)(A0 + arow * 40 + akh) = h0;
        *(s8_t*)(A0 + arow * 40 + akh + 8) = h1;
    }

#pragma unroll 1
    for (int k0 = 0; k0 < 16; k0++) {
        unsigned short* cur = (k0 & 1) ? A1 : A0;
        unsigned short* nxt = (k0 & 1) ? A0 : A1;
        bool more = k0 < 15;
        if (more) {
            const float* ap = aptr + (k0 + 1) * 32;
            ar0 = *(const f4_t*)(ap);  ar1 = *(const f4_t*)(ap + 4);
            ar2 = *(const f4_t*)(ap + 8); ar3 = *(const f4_t*)(ap + 12);
        }
        // B fragments for this k-step: direct global (L2-resident)
        s8_t bf[4];
#pragma unroll
        for (int nt = 0; nt < 4; nt++)
            bf[nt] = *(const s8_t*)(bptr + (size_t)nt * 16 * D_ + k0 * 32);
        __syncthreads();   // collective: A store of k0 visible; all waves done reading nxt
        s8_t af[8];
#pragma unroll
        for (int mt = 0; mt < 8; mt++)
            af[mt] = *(const s8_t*)(cur + (mt * 16 + mm) * 40 + qd * 8);
#pragma unroll
        for (int mt = 0; mt < 8; mt++)
#pragma unroll
            for (int nt = 0; nt < 4; nt++)
                acc[mt][nt] = __builtin_amdgcn_mfma_f32_16x16x32_bf16(
                    af[mt], bf[nt], acc[mt][nt], 0, 0, 0);
        if (more) {
            s8_t h0, h1;
            h0[0]=(short)f2bf(ar0[0]); h0[1]=(short)f2bf(ar0[1]); h0[2]=(short)f2bf(ar0[2]); h0[3]=(short)f2bf(ar0[3]);
            h0[4]=(short)f2bf(ar1[0]); h0[5]=(short)f2bf(ar1[1]); h0[6]=(short)f2bf(ar1[2]); h0[7]=(short)f2bf(ar1[3]);
            h1[0]=(short)f2bf(ar2[0]); h1[1]=(short)f2bf(ar2[1]); h1[2]=(short)f2bf(ar2[2]); h1[3]=(short)f2bf(ar2[3]);
            h1[4]=(short)f2bf(ar3[0]); h1[5]=(short)f2bf(ar3[1]); h1[6]=(short)f2bf(ar3[2]); h1[7]=(short)f2bf(ar3[3]);
            *(s8_t*)(nxt + arow * 40 + akh) = h0;
            *(s8_t*)(nxt + arow * 40 + akh + 8) = h1;
        }
    }

    // -------- epilogue: four 32-row halves through LDS; branch-free masked reductions ----
    // NOTE: h-loop MUST stay fully unrolled — runtime acc index spills the whole
    // accumulator to scratch (R3: 2.07 GB WRITE_SIZE, 16x slowdown).
    float cm = NEG_INF, cs = 0.f;
    const int mw = bIdx >> 6, mb = bIdx & 63;

#pragma unroll
    for (int h = 0; h < 4; h++) {
        __syncthreads();
#pragma unroll
        for (int mt2 = 0; mt2 < 2; mt2++) {
            int mt = h * 2 + mt2;
            int rl = mt2 * 16 + qd * 4;
#pragma unroll
            for (int nt = 0; nt < 4; nt++) {
                int col = wave * 64 + nt * 16 + mm;
#pragma unroll
                for (int r = 0; r < 4; r++)
                    Sh[(rl + r) * 257 + col] = acc[mt][nt][r];
            }
        }
        if (tid < 32) {
            int l = l0 + h * 32 + tid;
            rvadj[tid] = ((mbits[l * 4 + mw] >> mb) & 1ULL) ? 0.f : NEG_INF;
        }
        __syncthreads();

        // cross partial for column tid (exclusion of col==bIdx applied at the end)
        {
            float m2 = NEG_INF;
#pragma unroll 8
            for (int r = 0; r < 32; r++)
                m2 = fmaxf(m2, Sh[r * 257 + tid] + rvadj[r]);
            if (m2 > NEG_INF) {
                float s2 = 0.f;
#pragma unroll 8
                for (int r = 0; r < 32; r++)
                    s2 += __expf(Sh[r * 257 + tid] + rvadj[r] - m2);
                float M = fmaxf(cm, m2);
                cs = cs * __expf(cm - M) + s2 * __expf(m2 - M);
                cm = M;
            }
        }
        // denom partials: 128 threads, (row = tid&31, grp = tid>>5 covering 64 cols)
        if (tid < 128) {
            int row = tid & 31, grp = tid >> 5;
            int l = l0 + h * 32 + row;
            unsigned long long bits = mbits[l * 4 + grp];
            const float* Srow = Sh + row * 257 + grp * 64;
            float m = NEG_INF;
#pragma unroll 8
            for (int c = 0; c < 64; c++) {
                float adj = ((bits >> c) & 1ULL) ? 0.f : NEG_INF;
                m = fmaxf(m, Srow[c] + adj);
            }
            float s = 0.f;
            if (m > NEG_INF) {
#pragma unroll 8
                for (int c = 0; c < 64; c++) {
                    float adj = ((bits >> c) & 1ULL) ? 0.f : NEG_INF;
                    s += __expf(Srow[c] + adj - m);
                }
            }
            pm[grp * 32 + row] = m;
            ps[grp * 32 + row] = s;
        }
        __syncthreads();
        if (tid < 32) {
            float m0 = pm[tid], m1 = pm[32 + tid], m2 = pm[64 + tid], m3 = pm[96 + tid];
            float M = fmaxf(fmaxf(m0, m1), fmaxf(m2, m3));
            float dl;
            if (M == NEG_INF) dl = NEG_INF;
            else {
                float s = ps[tid] * __expf(m0 - M) + ps[32 + tid] * __expf(m1 - M) +
                          ps[64 + tid] * __expf(m2 - M) + ps[96 + tid] * __expf(m3 - M);
                dl = M + __logf(s);
            }
            int gr = row0 + h * 32 + tid;
            denom[gr] = dl;
            siji[gr] = Sh[tid * 257 + bIdx];
        }
    }
    if (tid == bIdx) { cm = NEG_INF; cs = 0.f; }    // k == i exclusion
    crossM[(size_t)tid * NT2 + tile] = cm;
    crossS[(size_t)tid * NT2 + tile] = cs;
}

// ---------------- K3: cross_log[i] = merge of 1024 (m,s) partials ----------------
__global__ __launch_bounds__(256) void cross_combine_kernel(const float* __restrict__ crossM,
                                                            const float* __restrict__ crossS,
                                                            float* __restrict__ crossLog) {
    int i = blockIdx.x;
    int tid = threadIdx.x;
    float m = NEG_INF, s = 0.f;
    for (int e = 0; e < NT2 / 256; e++) {
        int t = e * 256 + tid;
        float m2 = crossM[(size_t)i * NT2 + t];
        float s2 = crossS[(size_t)i * NT2 + t];
        if (m2 > NEG_INF) {
            if (m == NEG_INF) { m = m2; s = s2; }
            else {
                float M = fmaxf(m, m2);
                s = s * expf(m - M) + s2 * expf(m2 - M);
                m = M;
            }
        }
    }
    __shared__ float sm[256], ss[256];
    sm[tid] = m; ss[tid] = s;
    __syncthreads();
    for (int off = 128; off > 0; off >>= 1) {
        if (tid < off) {
            float m1 = sm[tid], s1 = ss[tid];
            float m2 = sm[tid + off], s2 = ss[tid + off];
            float M = fmaxf(m1, m2);
            float sv;
            if (M == NEG_INF) sv = 0.f;
            else sv = s1 * expf(m1 - M) + s2 * expf(m2 - M);
            sm[tid] = M; ss[tid] = sv;
        }
        __syncthreads();
    }
    if (tid == 0) crossLog[i] = (sm[0] == NEG_INF) ? NEG_INF : sm[0] + logf(ss[0]);
}

// ---------------- K4: per-block partial loss sums ----------------
__global__ __launch_bounds__(256) void loss_partial_kernel(
    const int* __restrict__ pad, const float* __restrict__ denom,
    const float* __restrict__ siji, const float* __restrict__ crossLog,
    float* __restrict__ psum, float* __restrict__ pcnt) {
    int tid = threadIdx.x;
    int idx = blockIdx.x * 256 + tid;
    float term = 0.f, cnt = 0.f;
    if (pad[idx] == 0) {
        float dl = denom[idx], sv = siji[idx], cl = crossLog[idx >> 9];
        float M = fmaxf(sv, cl);
        float neg = M + log1pf(expf(-fabsf(sv - cl)));
        term = 0.5f * (dl + neg) - sv;
        cnt = 1.f;
    }
    __shared__ float bs[256], bc[256];
    bs[tid] = term; bc[tid] = cnt;
    __syncthreads();
    for (int off = 128; off > 0; off >>= 1) {
        if (tid < off) { bs[tid] += bs[tid + off]; bc[tid] += bc[tid + off]; }
        __syncthreads();
    }
    if (tid == 0) { psum[blockIdx.x] = bs[0]; pcnt[blockIdx.x] = bc[0]; }
}

// ---------------- K5: final reduce of 512 partials ----------------
__global__ __launch_bounds__(256) void final_kernel(const float* __restrict__ psum,
                                                    const float* __restrict__ pcnt,
                                                    float* __restrict__ out) {
    int tid = threadIdx.x;
    __shared__ float bs[256], bc[256];
    bs[tid] = psum[tid] + psum[tid + 256];
    bc[tid] = pcnt[tid] + pcnt[tid + 256];
    __syncthreads();
    for (int off = 128; off > 0; off >>= 1) {
        if (tid < off) { bs[tid] += bs[tid + off]; bc[tid] += bc[tid + off]; }
        __syncthreads();
    }
    if (tid == 0) out[0] = bs[0] / bc[0];
}

extern "C" void kernel_launch(void* const* d_in, const int* in_sizes, int n_in,
                              void* d_out, int out_size, void* d_ws, size_t ws_size,
                              hipStream_t stream) {
    (void)in_sizes; (void)n_in; (void)out_size; (void)ws_size;
    const float* text = (const float*)d_in[0];
    const float* img  = (const float*)d_in[1];
    const float* Wml  = (const float*)d_in[2];
    const float* Wmv  = (const float*)d_in[3];
    const float* tau  = (const float*)d_in[4];
    const int* pad    = (const int*)d_in[5];
    float* out = (float*)d_out;

    float* ws = (float*)d_ws;
    float* ip       = ws;                      // 131072 fl
    unsigned short* Cb = (unsigned short*)(ws + 131072);  // 131072 ushort
    unsigned long long* mbits = (unsigned long long*)(ws + 262144); // 2048 u64
    float* denom    = ws + 266240;             // 131072
    float* siji     = ws + 397312;             // 131072
    float* crossM   = ws + 528384;             // 262144 (256 x 1024)
    float* crossS   = ws + 790528;             // 262144
    float* crossLog = ws + 1052672;            // 256
    float* psum     = ws + 1052928;            // 512
    float* pcnt     = ws + 1053440;            // 512

    hipLaunchKernelGGL(ip_kernel,   dim3(64),  dim3(256), 0, stream, img, Wmv, ip);
    hipLaunchKernelGGL(c_kernel,    dim3(64),  dim3(256), 0, stream, ip, Wml, tau, Cb);
    hipLaunchKernelGGL(mask_kernel, dim3(L_),  dim3(256), 0, stream, pad, mbits);
    hipLaunchKernelGGL(gemm_mfma_kernel, dim3(NT2), dim3(256), 0, stream,
                       text, Cb, mbits, denom, siji, crossM, crossS);
    hipLaunchKernelGGL(cross_combine_kernel, dim3(B_), dim3(256), 0, stream,
                       crossM, crossS, crossLog);
    hipLaunchKernelGGL(loss_partial_kernel, dim3(ROWS / 256), dim3(256), 0, stream,
                       pad, denom, siji, crossLog, psum, pcnt);
    hipLaunchKernelGGL(final_kernel, dim3(1), dim3(256), 0, stream, psum, pcnt, out);
}

// Round 7
// 501.995 us; speedup vs baseline: 1.1257x; 1.1257x over previous
//
#include <hip/hip_runtime.h>
#include <math.h>

// LCGLoss: B=256, L=512, D=512.
// S[(b,l),k] = (text @ C^T)[(b,l),k],  Cb[k][d] = bf16( (ip @ W_ML)[k][d] / tau )
// loss = mean over valid (i,l) of 0.5*(denom_log + logaddexp(s_iji, cross_log[i])) - s_iji

#define B_ 256
#define L_ 512
#define D_ 512
#define ROWS (B_ * L_)      // 131072
#define NT (ROWS / 64)      // 2048 row-tiles (M=64)
#define NEG_INF (-INFINITY)

typedef __attribute__((ext_vector_type(8))) short s8_t;     // 8 bf16 in 4 VGPRs
typedef __attribute__((ext_vector_type(4))) float f4_t;
typedef __attribute__((ext_vector_type(2))) float f2_t;
typedef __attribute__((ext_vector_type(4))) unsigned short us4_t;

__device__ inline unsigned short f2bf(float x) {
    unsigned int u = __float_as_uint(x);
    u += 0x7FFFu + ((u >> 16) & 1u);          // round-to-nearest-even
    return (unsigned short)(u >> 16);
}

typedef const __attribute__((address_space(1))) unsigned int as1_uint;
typedef __attribute__((address_space(3))) unsigned int as3_uint;
// async global->LDS, 16B per lane; LDS dest = wave-uniform base + lane*16
__device__ __attribute__((always_inline)) inline void gl_lds16(const void* g, void* l) {
    __builtin_amdgcn_global_load_lds((as1_uint*)g, (as3_uint*)l, 16, 0, 0);
}

// ---------------- K0: ip[k][e] = sum_d img[k][d]*Wmv[e][d]; 32k x 64e tiles, 64 blocks ----
__global__ __launch_bounds__(256) void ip_kernel(const float* __restrict__ img,
                                                 const float* __restrict__ Wmv,
                                                 float* __restrict__ ip) {
    int kt = blockIdx.x >> 3, et = blockIdx.x & 7;
    __shared__ float Ast[32][36];   // [d][krow]  (transposed)
    __shared__ float Bst[32][72];   // [d][ecol]  (transposed)
    int tid = threadIdx.x;
    int ty = tid >> 4;
    int tx = tid & 15;
    float acc[2][4] = {};
    int sr = tid >> 3, sc = (tid & 7) * 4;
    for (int d0 = 0; d0 < D_; d0 += 32) {
        f4_t a = *(const f4_t*)(img + (size_t)(kt * 32 + sr) * D_ + d0 + sc);
        f4_t b0 = *(const f4_t*)(Wmv + (size_t)(et * 64 + sr) * D_ + d0 + sc);
        f4_t b1 = *(const f4_t*)(Wmv + (size_t)(et * 64 + sr + 32) * D_ + d0 + sc);
        __syncthreads();
#pragma unroll
        for (int m = 0; m < 4; m++) {
            Ast[sc + m][sr] = a[m];
            Bst[sc + m][sr] = b0[m];
            Bst[sc + m][sr + 32] = b1[m];
        }
        __syncthreads();
#pragma unroll 4
        for (int d = 0; d < 32; d++) {
            f2_t a2 = *(const f2_t*)&Ast[d][ty * 2];
            f4_t b4 = *(const f4_t*)&Bst[d][tx * 4];
#pragma unroll
            for (int i = 0; i < 2; i++)
#pragma unroll
                for (int j = 0; j < 4; j++) acc[i][j] = fmaf(a2[i], b4[j], acc[i][j]);
        }
    }
#pragma unroll
    for (int i = 0; i < 2; i++) {
        f4_t o; o[0] = acc[i][0]; o[1] = acc[i][1]; o[2] = acc[i][2]; o[3] = acc[i][3];
        *(f4_t*)(ip + (size_t)(kt * 32 + ty * 2 + i) * D_ + et * 64 + tx * 4) = o;
    }
}

// ---------------- K1: Cb[k][d] = bf16( sum_e ip[k][e]*Wml[e][d] / tau ); 64 blocks -------
__global__ __launch_bounds__(256) void c_kernel(const float* __restrict__ ip,
                                                const float* __restrict__ Wml,
                                                const float* __restrict__ tau,
                                                unsigned short* __restrict__ Cb) {
    int kt = blockIdx.x >> 3, dt = blockIdx.x & 7;
    __shared__ float Ast[32][36];
    __shared__ float Bst[32][72];
    int tid = threadIdx.x;
    int ty = tid >> 4;
    int tx = tid & 15;
    float acc[2][4] = {};
    int sr = tid >> 3, sc = (tid & 7) * 4;
    int br = tid >> 4, bc = (tid & 15) * 4;
    for (int e0 = 0; e0 < D_; e0 += 32) {
        f4_t a = *(const f4_t*)(ip + (size_t)(kt * 32 + sr) * D_ + e0 + sc);
        f4_t b0 = *(const f4_t*)(Wml + (size_t)(e0 + br) * D_ + dt * 64 + bc);
        f4_t b1 = *(const f4_t*)(Wml + (size_t)(e0 + br + 16) * D_ + dt * 64 + bc);
        __syncthreads();
#pragma unroll
        for (int m = 0; m < 4; m++) Ast[sc + m][sr] = a[m];
        *(f4_t*)&Bst[br][bc] = b0;
        *(f4_t*)&Bst[br + 16][bc] = b1;
        __syncthreads();
#pragma unroll 4
        for (int e = 0; e < 32; e++) {
            f2_t a2 = *(const f2_t*)&Ast[e][ty * 2];
            f4_t b4 = *(const f4_t*)&Bst[e][tx * 4];
#pragma unroll
            for (int i = 0; i < 2; i++)
#pragma unroll
                for (int j = 0; j < 4; j++) acc[i][j] = fmaf(a2[i], b4[j], acc[i][j]);
        }
    }
    float it = 1.0f / fmaxf(tau[0], 0.001f);
#pragma unroll
    for (int i = 0; i < 2; i++) {
        us4_t o;
#pragma unroll
        for (int j = 0; j < 4; j++) o[j] = f2bf(acc[i][j] * it);
        *(us4_t*)(Cb + (size_t)(kt * 32 + ty * 2 + i) * D_ + dt * 64 + tx * 4) = o;
    }
}

// ---------------- Kmask: mbits[l*4+w] bit j = valid[w*64+j, l] ----------------
__global__ __launch_bounds__(256) void mask_kernel(const int* __restrict__ pad,
                                                   unsigned long long* __restrict__ mbits) {
    int l = blockIdx.x;
    int w = threadIdx.x >> 6;
    int j = threadIdx.x & 63;
    unsigned long long bal = __ballot(pad[(w * 64 + j) * L_ + l] == 0);
    if (j == 0) mbits[l * 4 + w] = bal;
}

// ---------------- K2: MFMA GEMM, M=64 x N=256, BK=64, global_load_lds staging ------------
// A (f32, 16 KB) and B (bf16, 32 KB) staged direct-to-LDS with XOR-swizzled layouts
// (global_load_lds forbids padding; swizzle makes frag ds_read_b128s conflict-free).
// A layout: chunk16B index = row*16 + (j ^ ((row&7)<<1)), row=0..63, j=0..15 (4 f32 each)
// B layout: byte 16384 + col*128 + (j ^ (col&7))*16,      col=0..255, j=0..7 (8 bf16 each)
__global__ __launch_bounds__(256) void gemm_mfma_kernel(
    const float* __restrict__ text, const unsigned short* __restrict__ Cb,
    const unsigned long long* __restrict__ mbits,
    float* __restrict__ denom, float* __restrict__ siji,
    float* __restrict__ crossM, float* __restrict__ crossS) {
    // 48 KB LDS: staging A [0,16384) B [16384,49152); epilogue overlay 8512 floats
    __shared__ __align__(16) float lds[12288];
    float* Sh  = lds;
    float* pm  = lds + 8224;
    float* ps  = lds + 8352;
    float* rvadj = lds + 8480;

    const int tile = blockIdx.x;
    const int row0 = tile * 64;
    const int bIdx = row0 >> 9;
    const int l0 = row0 & 511;
    const int tid = threadIdx.x;
    const int wave = tid >> 6;
    const int lane = tid & 63;
    const int qd = lane >> 4;
    const int mm = lane & 15;

    f4_t acc[4][4];
#pragma unroll
    for (int mt = 0; mt < 4; mt++)
#pragma unroll
        for (int nt = 0; nt < 4; nt++)
#pragma unroll
            for (int r = 0; r < 4; r++) acc[mt][nt][r] = 0.f;

    char* ldsc = (char*)lds;

#pragma unroll 1
    for (int k0 = 0; k0 < D_; k0 += 64) {
        __syncthreads();               // prev compute done reading LDS
        // A: 1024 chunks of 16B (64 rows x 16), 4 instrs x 256 threads
#pragma unroll
        for (int i = 0; i < 4; i++) {
            int c = i * 256 + tid;
            int row = c >> 4, j = c & 15;
            int jg = j ^ ((row & 7) << 1);
            const float* g = text + (size_t)(row0 + row) * D_ + k0 + jg * 4;
            gl_lds16(g, ldsc + (i * 256 + wave * 64) * 16);
        }
        // B: 2048 chunks of 16B (256 cols x 8), 8 instrs x 256 threads
#pragma unroll
        for (int i = 0; i < 8; i++) {
            int c = i * 256 + tid;
            int col = c >> 3, j = c & 7;
            int jg = j ^ (col & 7);
            const unsigned short* g = Cb + (size_t)col * D_ + k0 + jg * 8;
            gl_lds16(g, ldsc + 16384 + (i * 256 + wave * 64) * 16);
        }
        __syncthreads();               // vmcnt(0) drain before barrier -> LDS visible
#pragma unroll
        for (int s = 0; s < 2; s++) {  // two K=32 MFMA sub-steps
            s8_t af[4], bf[4];
#pragma unroll
            for (int mt = 0; mt < 4; mt++) {
                int row = mt * 16 + mm;
                int j0 = (s * 8 + qd * 2) ^ ((mm & 7) << 1);   // even: chunk pair contiguous
                const f4_t* ap = (const f4_t*)(ldsc + row * 256 + j0 * 16);
                f4_t x0 = ap[0], x1 = ap[1];
                s8_t h;
                h[0] = (short)f2bf(x0[0]); h[1] = (short)f2bf(x0[1]);
                h[2] = (short)f2bf(x0[2]); h[3] = (short)f2bf(x0[3]);
                h[4] = (short)f2bf(x1[0]); h[5] = (short)f2bf(x1[1]);
                h[6] = (short)f2bf(x1[2]); h[7] = (short)f2bf(x1[3]);
                af[mt] = h;
            }
#pragma unroll
            for (int nt = 0; nt < 4; nt++) {
                int col = wave * 64 + nt * 16 + mm;
                int j = (s * 4 + qd) ^ (mm & 7);
                bf[nt] = *(const s8_t*)(ldsc + 16384 + col * 128 + j * 16);
            }
#pragma unroll
            for (int mt = 0; mt < 4; mt++)
#pragma unroll
                for (int nt = 0; nt < 4; nt++)
                    acc[mt][nt] = __builtin_amdgcn_mfma_f32_16x16x32_bf16(
                        af[mt], bf[nt], acc[mt][nt], 0, 0, 0);
        }
    }

    // -------- epilogue: two 32-row halves through LDS; branch-free masked reductions -----
    // NOTE: h-loop MUST stay fully unrolled — runtime acc index spills the whole
    // accumulator to scratch (R3: 2.07 GB WRITE_SIZE, 16x slowdown).
    float cm = NEG_INF, cs = 0.f;
    const int mw = bIdx >> 6, mb = bIdx & 63;

#pragma unroll
    for (int h = 0; h < 2; h++) {
        __syncthreads();
#pragma unroll
        for (int mt2 = 0; mt2 < 2; mt2++) {
            int mt = h * 2 + mt2;
            int rl = mt2 * 16 + qd * 4;
#pragma unroll
            for (int nt = 0; nt < 4; nt++) {
                int col = wave * 64 + nt * 16 + mm;
#pragma unroll
                for (int r = 0; r < 4; r++)
                    Sh[(rl + r) * 257 + col] = acc[mt][nt][r];
            }
        }
        if (tid < 32) {
            int l = l0 + h * 32 + tid;
            rvadj[tid] = ((mbits[l * 4 + mw] >> mb) & 1ULL) ? 0.f : NEG_INF;
        }
        __syncthreads();

        // cross partial for column tid (exclusion of col==bIdx applied at the end)
        {
            float m2 = NEG_INF;
#pragma unroll 8
            for (int r = 0; r < 32; r++)
                m2 = fmaxf(m2, Sh[r * 257 + tid] + rvadj[r]);
            if (m2 > NEG_INF) {
                float s2 = 0.f;
#pragma unroll 8
                for (int r = 0; r < 32; r++)
                    s2 += __expf(Sh[r * 257 + tid] + rvadj[r] - m2);
                float M = fmaxf(cm, m2);
                cs = cs * __expf(cm - M) + s2 * __expf(m2 - M);
                cm = M;
            }
        }
        // denom partials: 128 threads, (row = tid&31, grp = tid>>5 covering 64 cols)
        if (tid < 128) {
            int row = tid & 31, grp = tid >> 5;
            int l = l0 + h * 32 + row;
            unsigned long long bits = mbits[l * 4 + grp];
            const float* Srow = Sh + row * 257 + grp * 64;
            float m = NEG_INF;
#pragma unroll 8
            for (int c = 0; c < 64; c++) {
                float adj = ((bits >> c) & 1ULL) ? 0.f : NEG_INF;
                m = fmaxf(m, Srow[c] + adj);
            }
            float s = 0.f;
            if (m > NEG_INF) {
#pragma unroll 8
                for (int c = 0; c < 64; c++) {
                    float adj = ((bits >> c) & 1ULL) ? 0.f : NEG_INF;
                    s += __expf(Srow[c] + adj - m);
                }
            }
            pm[grp * 32 + row] = m;
            ps[grp * 32 + row] = s;
        }
        __syncthreads();
        if (tid < 32) {
            float m0 = pm[tid], m1 = pm[32 + tid], m2 = pm[64 + tid], m3 = pm[96 + tid];
            float M = fmaxf(fmaxf(m0, m1), fmaxf(m2, m3));
            float dl;
            if (M == NEG_INF) dl = NEG_INF;
            else {
                float s = ps[tid] * __expf(m0 - M) + ps[32 + tid] * __expf(m1 - M) +
                          ps[64 + tid] * __expf(m2 - M) + ps[96 + tid] * __expf(m3 - M);
                dl = M + __logf(s);
            }
            int gr = row0 + h * 32 + tid;
            denom[gr] = dl;
            siji[gr] = Sh[tid * 257 + bIdx];
        }
    }
    if (tid == bIdx) { cm = NEG_INF; cs = 0.f; }    // k == i exclusion
    crossM[(size_t)tid * NT + tile] = cm;
    crossS[(size_t)tid * NT + tile] = cs;
}

// ---------------- K3: cross_log[i] = merge of 2048 (m,s) partials ----------------
__global__ __launch_bounds__(256) void cross_combine_kernel(const float* __restrict__ crossM,
                                                            const float* __restrict__ crossS,
                                                            float* __restrict__ crossLog) {
    int i = blockIdx.x;
    int tid = threadIdx.x;
    float m = NEG_INF, s = 0.f;
    for (int e = 0; e < NT / 256; e++) {
        int t = e * 256 + tid;
        float m2 = crossM[(size_t)i * NT + t];
        float s2 = crossS[(size_t)i * NT + t];
        if (m2 > NEG_INF) {
            if (m == NEG_INF) { m = m2; s = s2; }
            else {
                float M = fmaxf(m, m2);
                s = s * expf(m - M) + s2 * expf(m2 - M);
                m = M;
            }
        }
    }
    __shared__ float sm[256], ss[256];
    sm[tid] = m; ss[tid] = s;
    __syncthreads();
    for (int off = 128; off > 0; off >>= 1) {
        if (tid < off) {
            float m1 = sm[tid], s1 = ss[tid];
            float m2 = sm[tid + off], s2 = ss[tid + off];
            float M = fmaxf(m1, m2);
            float sv;
            if (M == NEG_INF) sv = 0.f;
            else sv = s1 * expf(m1 - M) + s2 * expf(m2 - M);
            sm[tid] = M; ss[tid] = sv;
        }
        __syncthreads();
    }
    if (tid == 0) crossLog[i] = (sm[0] == NEG_INF) ? NEG_INF : sm[0] + logf(ss[0]);
}

// ---------------- K4: per-block partial loss sums ----------------
__global__ __launch_bounds__(256) void loss_partial_kernel(
    const int* __restrict__ pad, const float* __restrict__ denom,
    const float* __restrict__ siji, const float* __restrict__ crossLog,
    float* __restrict__ psum, float* __restrict__ pcnt) {
    int tid = threadIdx.x;
    int idx = blockIdx.x * 256 + tid;
    float term = 0.f, cnt = 0.f;
    if (pad[idx] == 0) {
        float dl = denom[idx], sv = siji[idx], cl = crossLog[idx >> 9];
        float M = fmaxf(sv, cl);
        float neg = M + log1pf(expf(-fabsf(sv - cl)));
        term = 0.5f * (dl + neg) - sv;
        cnt = 1.f;
    }
    __shared__ float bs[256], bc[256];
    bs[tid] = term; bc[tid] = cnt;
    __syncthreads();
    for (int off = 128; off > 0; off >>= 1) {
        if (tid < off) { bs[tid] += bs[tid + off]; bc[tid] += bc[tid + off]; }
        __syncthreads();
    }
    if (tid == 0) { psum[blockIdx.x] = bs[0]; pcnt[blockIdx.x] = bc[0]; }
}

// ---------------- K5: final reduce of 512 partials ----------------
__global__ __launch_bounds__(256) void final_kernel(const float* __restrict__ psum,
                                                    const float* __restrict__ pcnt,
                                                    float* __restrict__ out) {
    int tid = threadIdx.x;
    __shared__ float bs[256], bc[256];
    bs[tid] = psum[tid] + psum[tid + 256];
    bc[tid] = pcnt[tid] + pcnt[tid + 256];
    __syncthreads();
    for (int off = 128; off > 0; off >>= 1) {
        if (tid < off) { bs[tid] += bs[tid + off]; bc[tid] += bc[tid + off]; }
        __syncthreads();
    }
    if (tid == 0) out[0] = bs[0] / bc[0];
}

extern "C" void kernel_launch(void* const* d_in, const int* in_sizes, int n_in,
                              void* d_out, int out_size, void* d_ws, size_t ws_size,
                              hipStream_t stream) {
    (void)in_sizes; (void)n_in; (void)out_size; (void)ws_size;
    const float* text = (const float*)d_in[0];
    const float* img  = (const float*)d_in[1];
    const float* Wml  = (const float*)d_in[2];
    const float* Wmv  = (const float*)d_in[3];
    const float* tau  = (const float*)d_in[4];
    const int* pad    = (const int*)d_in[5];
    float* out = (float*)d_out;

    float* ws = (float*)d_ws;
    float* ip       = ws;                      // 131072 fl
    unsigned short* Cb = (unsigned short*)(ws + 131072);  // 131072 ushort
    unsigned long long* mbits = (unsigned long long*)(ws + 262144); // 2048 u64
    float* denom    = ws + 266240;             // 131072
    float* siji     = ws + 397312;             // 131072
    float* crossM   = ws + 528384;             // 524288 (256 x 2048)
    float* crossS   = ws + 1052672;            // 524288
    float* crossLog = ws + 1576960;            // 256
    float* psum     = ws + 1577216;            // 512
    float* pcnt     = ws + 1577728;            // 512

    hipLaunchKernelGGL(ip_kernel,   dim3(64),  dim3(256), 0, stream, img, Wmv, ip);
    hipLaunchKernelGGL(c_kernel,    dim3(64),  dim3(256), 0, stream, ip, Wml, tau, Cb);
    hipLaunchKernelGGL(mask_kernel, dim3(L_),  dim3(256), 0, stream, pad, mbits);
    hipLaunchKernelGGL(gemm_mfma_kernel, dim3(NT), dim3(256), 0, stream,
                       text, Cb, mbits, denom, siji, crossM, crossS);
    hipLaunchKernelGGL(cross_combine_kernel, dim3(B_), dim3(256), 0, stream,
                       crossM, crossS, crossLog);
    hipLaunchKernelGGL(loss_partial_kernel, dim3(ROWS / 256), dim3(256), 0, stream,
                       pad, denom, siji, crossLog, psum, pcnt);
    hipLaunchKernelGGL(final_kernel, dim3(1), dim3(256), 0, stream, psum, pcnt, out);
}